// Round 1
// baseline (641.564 us; speedup 1.0000x reference)
//
#include <hip/hip_runtime.h>
#include <stdint.h>

#define K_CB 32768
#define TDIM 768
#define KB 64
#define TC 64
#define NCHUNK 12
#define MT 8
#define NT 4

__device__ __forceinline__ unsigned long long fkey(float f, unsigned idx) {
    unsigned u = __float_as_uint(f);
    u = (u & 0x80000000u) ? ~u : (u | 0x80000000u);
    return ((unsigned long long)u << 32) | (unsigned long long)idx;
}
__device__ __forceinline__ unsigned long long umin64(unsigned long long a, unsigned long long b) {
    return a < b ? a : b;
}

// ---------------------------------------------------------------------------
// Kernel 1: build XS[row=256][t=768] (row = a*16+i, t = (p*48+q)*8+j, matching
// codebook entry layout), xsum_lo/hi per row, and init the 368-entry scoreboard.
// ---------------------------------------------------------------------------
extern "C" __global__ __launch_bounds__(256)
void prep_kernel(const float* __restrict__ x, float* __restrict__ XS,
                 float* __restrict__ xsum, unsigned long long* __restrict__ sb) {
    __shared__ float xbuf[TDIM];
    const int row = blockIdx.x;          // 0..255
    const int a = row >> 4, i = row & 15;
    for (int pass = 0; pass < 3; ++pass) {
        int t = pass * 256 + threadIdx.x;          // 0..767
        int g = t >> 3, j = t & 7;
        int p = g / 48, q = g - 48 * p;
        float v = x[((size_t)(a * 2 + p) * 126 + (19 + q)) * 128 + (i * 8 + j)];
        XS[(size_t)row * TDIM + t] = v;
        xbuf[t] = v;
    }
    __syncthreads();
    if (threadIdx.x < 2) {
        // deterministic sequential sum, lo (j<4) for tid 0, hi (j>=4) for tid 1
        int off = threadIdx.x ? 4 : 0;
        float s = 0.f;
        for (int g = 0; g < 96; ++g)
            for (int j = 0; j < 4; ++j)
                s += xbuf[g * 8 + off + j];
        xsum[threadIdx.x * 256 + row] = s;
    }
    if (row == 0) {
        for (int t = threadIdx.x; t < 368; t += 256) sb[t] = ~0ULL;
    }
}

// ---------------------------------------------------------------------------
// Kernel 2: per-codebook-entry stats: csum_lo/hi, csq_lo/hi. One wave per entry.
// ---------------------------------------------------------------------------
extern "C" __global__ __launch_bounds__(256)
void stats_kernel(const float* __restrict__ cb, float* __restrict__ stats) {
    const int wid = threadIdx.x >> 6, lane = threadIdx.x & 63;
    const int k = blockIdx.x * 4 + wid;
    const float* e = cb + (size_t)k * TDIM;
    const int j = lane & 7;
    float sl = 0.f, sh = 0.f, ql = 0.f, qh = 0.f;
    for (int it = 0; it < 12; ++it) {
        float v = e[it * 64 + lane];
        if (j < 4) { sl += v; ql += v * v; }
        else       { sh += v; qh += v * v; }
    }
    for (int m = 1; m < 64; m <<= 1) {
        sl += __shfl_xor(sl, m); sh += __shfl_xor(sh, m);
        ql += __shfl_xor(ql, m); qh += __shfl_xor(qh, m);
    }
    if (lane == 0) {
        stats[k]            = sl;
        stats[K_CB + k]     = sh;
        stats[2 * K_CB + k] = ql;
        stats[3 * K_CB + k] = qh;
    }
}

// ---------------------------------------------------------------------------
// Kernel 3: the heavy GEMM + scoring + argmin. Each block owns 64 codebook
// entries; loops 2 m-tiles of 128 rows. LDS tiles padded to stride 68 (bank-
// conflict-free b128). Thread tile: 8 rows x 4 cols, lo+hi accumulators.
// Mirror (1-c) scores derived algebraically. Scoreboard: u64 atomicMin,
// key = (sortable float bits << 32) | index  -> exact, order-independent,
// ties resolve to lowest index (matches jnp.argmin).
// ---------------------------------------------------------------------------
extern "C" __global__ __launch_bounds__(256, 2)
void gemm_kernel(const float* __restrict__ cb, const float* __restrict__ XS,
                 const float* __restrict__ xsum, const float* __restrict__ stats,
                 unsigned long long* __restrict__ sb) {
    __shared__ float xs_s[128][68];
    __shared__ float cb_s[64][68];
    const int tid = threadIdx.x;
    const int tr = tid >> 4;   // 0..15  (= i index of rows this thread touches)
    const int tc = tid & 15;   // 0..15
    const int k0 = blockIdx.x * KB;

    // preload this thread's 4 columns' stats (reused across both m-tiles)
    float stl[NT], sth[NT], stql[NT], stqh[NT];
#pragma unroll
    for (int nn = 0; nn < NT; ++nn) {
        int k = k0 + nn * 16 + tc;
        stl[nn]  = stats[k];
        sth[nn]  = stats[K_CB + k];
        stql[nn] = stats[2 * K_CB + k];
        stqh[nn] = stats[3 * K_CB + k];
    }

    for (int mt = 0; mt < 2; ++mt) {
        float acc_lo[MT][NT], acc_hi[MT][NT];
#pragma unroll
        for (int mm = 0; mm < MT; ++mm)
#pragma unroll
            for (int nn = 0; nn < NT; ++nn) { acc_lo[mm][nn] = 0.f; acc_hi[mm][nn] = 0.f; }

        for (int c = 0; c < NCHUNK; ++c) {
            __syncthreads();
            // stage xs: 128 rows x 64 t   (coalesced 16B/lane)
#pragma unroll
            for (int pass = 0; pass < 8; ++pass) {
                int r = pass * 16 + tr;
                float4 v = *(const float4*)&XS[(size_t)(mt * 128 + r) * TDIM + c * TC + tc * 4];
                *(float4*)&xs_s[r][tc * 4] = v;
            }
            // stage cb: 64 k x 64 t
#pragma unroll
            for (int pass = 0; pass < 4; ++pass) {
                int kk = pass * 16 + tr;
                float4 v = *(const float4*)&cb[(size_t)(k0 + kk) * TDIM + c * TC + tc * 4];
                *(float4*)&cb_s[kk][tc * 4] = v;
            }
            __syncthreads();
            // 8 (p,q) groups per chunk; j<4 -> lo, j>=4 -> hi
#pragma unroll
            for (int g = 0; g < 8; ++g) {
                float4 xl[MT], xh[MT];
#pragma unroll
                for (int mm = 0; mm < MT; ++mm) {
                    xl[mm] = *(const float4*)&xs_s[mm * 16 + tr][g * 8];
                    xh[mm] = *(const float4*)&xs_s[mm * 16 + tr][g * 8 + 4];
                }
                float4 cl[NT], ch[NT];
#pragma unroll
                for (int nn = 0; nn < NT; ++nn) {
                    cl[nn] = *(const float4*)&cb_s[nn * 16 + tc][g * 8];
                    ch[nn] = *(const float4*)&cb_s[nn * 16 + tc][g * 8 + 4];
                }
#pragma unroll
                for (int mm = 0; mm < MT; ++mm)
#pragma unroll
                    for (int nn = 0; nn < NT; ++nn) {
                        acc_lo[mm][nn] += xl[mm].x * cl[nn].x;
                        acc_lo[mm][nn] += xl[mm].y * cl[nn].y;
                        acc_lo[mm][nn] += xl[mm].z * cl[nn].z;
                        acc_lo[mm][nn] += xl[mm].w * cl[nn].w;
                        acc_hi[mm][nn] += xh[mm].x * ch[nn].x;
                        acc_hi[mm][nn] += xh[mm].y * ch[nn].y;
                        acc_hi[mm][nn] += xh[mm].z * ch[nn].z;
                        acc_hi[mm][nn] += xh[mm].w * ch[nn].w;
                    }
            }
        }

        // ---- scoring + argmin ----
        // row = mt*128 + mm*16 + tr  ->  a = mt*8 + mm, i = tr
#pragma unroll
        for (int mm = 0; mm < MT; ++mm) {
            const int a = mt * 8 + mm;
            const int ii = tr;
            const int row = mt * 128 + mm * 16 + tr;
            const float xl = xsum[row], xh = xsum[256 + row];
            unsigned long long kA = ~0ULL, kB = ~0ULL;
#pragma unroll
            for (int nn = 0; nn < NT; ++nn) {
                unsigned k = (unsigned)(k0 + nn * 16 + tc);
                float dl = acc_lo[mm][nn], dh = acc_hi[mm][nn];
                float lo_d = stql[nn] - 2.f * dl;
                float lo_m = (384.f - 2.f * stl[nn] + stql[nn]) - 2.f * (xl - dl);
                float hi_d = stqh[nn] - 2.f * dh;
                float hi_m = (384.f - 2.f * sth[nn] + stqh[nn]) - 2.f * (xh - dh);
                if (ii < 7) {
                    kA = umin64(kA, umin64(fkey(lo_d, k), fkey(lo_m, k + 32768u)));
                    kB = umin64(kB, umin64(fkey(hi_d, k), fkey(hi_m, k + 32768u)));
                } else {
                    float fu_d = lo_d + hi_d, fu_m = lo_m + hi_m;
                    kA = umin64(kA, umin64(fkey(fu_d, k), fkey(fu_m, k + 32768u)));
                }
            }
            // reduce across the 16 lanes sharing this row (xor masks stay in group)
#pragma unroll
            for (int m = 1; m < 16; m <<= 1) {
                kA = umin64(kA, __shfl_xor(kA, m));
                kB = umin64(kB, __shfl_xor(kB, m));
            }
            if (tc == 0) {
                if (ii < 7) {
                    atomicMin(&sb[a * 23 + ii], kA);
                    atomicMin(&sb[a * 23 + 7 + ii], kB);
                } else {
                    atomicMin(&sb[a * 23 + 14 + (ii - 7)], kA);
                }
            }
        }
    }
}

// ---------------------------------------------------------------------------
// Kernel 4: emit bits. out[a][0:6]=0; bit b: stream s=b/22, bit bb=b%22.
// ---------------------------------------------------------------------------
extern "C" __global__ __launch_bounds__(512)
void bits_kernel(const unsigned long long* __restrict__ sb, float* __restrict__ out) {
    const int a = blockIdx.x;
    const int pos = threadIdx.x;   // 0..511
    float v = 0.f;
    if (pos >= 6) {
        int b = pos - 6;
        int s = b / 22;
        int bb = b - s * 22;
        unsigned idx = (unsigned)(sb[a * 23 + s] & 0xFFFFFFFFu);
        v = (float)((idx >> bb) & 1u);
    }
    out[a * 512 + pos] = v;
}

extern "C" void kernel_launch(void* const* d_in, const int* in_sizes, int n_in,
                              void* d_out, int out_size, void* d_ws, size_t ws_size,
                              hipStream_t stream) {
    const float* x  = (const float*)d_in[0];   // [16,2,126,128]
    const float* cb = (const float*)d_in[1];   // [32768,2,48,8]
    float* ws    = (float*)d_ws;
    float* XS    = ws;                         // 256*768 floats
    float* xsum  = ws + 196608;                // 512 floats (lo then hi)
    float* stats = ws + 197120;                // 4*32768 floats
    unsigned long long* sb = (unsigned long long*)((char*)d_ws + (size_t)328192 * 4); // 368 u64
    float* out = (float*)d_out;

    prep_kernel<<<256, 256, 0, stream>>>(x, XS, xsum, sb);
    stats_kernel<<<K_CB / 4, 256, 0, stream>>>(cb, stats);
    gemm_kernel<<<K_CB / KB, 256, 0, stream>>>(cb, XS, xsum, stats, sb);
    bits_kernel<<<16, 512, 0, stream>>>(sb, out);
}

// Round 2
// 393.299 us; speedup vs baseline: 1.6312x; 1.6312x over previous
//
#include <hip/hip_runtime.h>
#include <stdint.h>

#define K_CB 32768
#define TDIM 768

__device__ __forceinline__ unsigned long long fkey(float f, unsigned idx) {
    unsigned u = __float_as_uint(f);
    u = (u & 0x80000000u) ? ~u : (u | 0x80000000u);
    return ((unsigned long long)u << 32) | (unsigned long long)idx;
}
__device__ __forceinline__ unsigned long long umin64(unsigned long long a, unsigned long long b) {
    return a < b ? a : b;
}

// ---------------------------------------------------------------------------
// Kernel 1: build XS[row=256][t=768] (row = a*16+i, t = (p*48+q)*8+j, matching
// codebook entry layout), xsum_lo/hi per row, and init the 368-entry scoreboard.
// ---------------------------------------------------------------------------
extern "C" __global__ __launch_bounds__(256)
void prep_kernel(const float* __restrict__ x, float* __restrict__ XS,
                 float* __restrict__ xsum, unsigned long long* __restrict__ sb) {
    __shared__ float xbuf[TDIM];
    const int row = blockIdx.x;          // 0..255
    const int a = row >> 4, i = row & 15;
    for (int pass = 0; pass < 3; ++pass) {
        int t = pass * 256 + threadIdx.x;          // 0..767
        int g = t >> 3, j = t & 7;
        int p = g / 48, q = g - 48 * p;
        float v = x[((size_t)(a * 2 + p) * 126 + (19 + q)) * 128 + (i * 8 + j)];
        XS[(size_t)row * TDIM + t] = v;
        xbuf[t] = v;
    }
    __syncthreads();
    if (threadIdx.x < 2) {
        // deterministic sequential sum, lo (j<4) for tid 0, hi (j>=4) for tid 1
        int off = threadIdx.x ? 4 : 0;
        float s = 0.f;
        for (int g = 0; g < 96; ++g)
            for (int j = 0; j < 4; ++j)
                s += xbuf[g * 8 + off + j];
        xsum[threadIdx.x * 256 + row] = s;
    }
    if (row == 0) {
        for (int t = threadIdx.x; t < 368; t += 256) sb[t] = ~0ULL;
    }
}

// ---------------------------------------------------------------------------
// Kernel 2: GEMM + fused codebook stats + scoring + argmin.
// Block: 64 codebook entries x 256 rows (2 m-tiles of 128), K=768 in 12
// chunks of 64. Register tile 8 rows x 4 cols, lo+hi accumulators (64 regs).
// Inner loop hoists 4 c-fragments (32 regs) and STREAMS x-fragments (8 regs)
// -> ~130 live VGPRs, fits the 168-reg cap of __launch_bounds__(256,3):
// 3 blocks/CU (LDS 53.2KB x3 = 159.7KB), no scratch spills.
// Codebook stats (csum/csq lo/hi) are accumulated from the staging float4s
// during mt==0 (parity of tc selects lo/hi), reduced via parity-preserving
// shfl_xor (masks 2,4,8), parked in LDS. Saves a separate 100MB read.
// Scoreboard: u64 atomicMin, key = sortable-float-bits<<32 | index -> exact,
// order-independent, ties resolve to lowest index (matches jnp.argmin).
// ---------------------------------------------------------------------------
extern "C" __global__ __launch_bounds__(256, 3)
void gemm_kernel(const float* __restrict__ cb, const float* __restrict__ XS,
                 const float* __restrict__ xsum,
                 unsigned long long* __restrict__ sb) {
    __shared__ float xs_s[128][68];
    __shared__ float cb_s[64][68];
    __shared__ float st_s[4][64];   // 0=csum_lo 1=csum_hi 2=csq_lo 3=csq_hi
    const int tid = threadIdx.x;
    const int tr = tid >> 4;   // 0..15
    const int tc = tid & 15;   // 0..15
    const int k0 = blockIdx.x * 64;

    float sp[4] = {0.f, 0.f, 0.f, 0.f};   // csum partial, per staging pass
    float qp[4] = {0.f, 0.f, 0.f, 0.f};   // csq  partial

    for (int mt = 0; mt < 2; ++mt) {
        float acc_lo[8][4], acc_hi[8][4];
#pragma unroll
        for (int mm = 0; mm < 8; ++mm)
#pragma unroll
            for (int nn = 0; nn < 4; ++nn) { acc_lo[mm][nn] = 0.f; acc_hi[mm][nn] = 0.f; }

        for (int c = 0; c < 12; ++c) {
            __syncthreads();
            // stage xs: 128 rows x 64 t (coalesced 16B/lane)
#pragma unroll
            for (int pass = 0; pass < 8; ++pass) {
                int r = pass * 16 + tr;
                float4 v = *(const float4*)&XS[(size_t)(mt * 128 + r) * TDIM + c * 64 + tc * 4];
                *(float4*)&xs_s[r][tc * 4] = v;
            }
            // stage cb: 64 k x 64 t; fold stats accumulation into the load
#pragma unroll
            for (int pass = 0; pass < 4; ++pass) {
                int kk = pass * 16 + tr;
                float4 v = *(const float4*)&cb[(size_t)(k0 + kk) * TDIM + c * 64 + tc * 4];
                *(float4*)&cb_s[kk][tc * 4] = v;
                if (mt == 0) {
                    sp[pass] += v.x + v.y + v.z + v.w;
                    qp[pass] += v.x * v.x + v.y * v.y + v.z * v.z + v.w * v.w;
                }
            }
            __syncthreads();
            // 8 (p,q) groups per chunk; j<4 -> lo, j>=4 -> hi
#pragma unroll
            for (int g = 0; g < 8; ++g) {
                float4 cl[4], ch[4];
#pragma unroll
                for (int nn = 0; nn < 4; ++nn) {
                    cl[nn] = *(const float4*)&cb_s[nn * 16 + tc][g * 8];
                    ch[nn] = *(const float4*)&cb_s[nn * 16 + tc][g * 8 + 4];
                }
#pragma unroll
                for (int mm = 0; mm < 8; ++mm) {
                    float4 xl = *(const float4*)&xs_s[mm * 16 + tr][g * 8];
                    float4 xh = *(const float4*)&xs_s[mm * 16 + tr][g * 8 + 4];
#pragma unroll
                    for (int nn = 0; nn < 4; ++nn) {
                        acc_lo[mm][nn] += xl.x * cl[nn].x;
                        acc_lo[mm][nn] += xl.y * cl[nn].y;
                        acc_lo[mm][nn] += xl.z * cl[nn].z;
                        acc_lo[mm][nn] += xl.w * cl[nn].w;
                        acc_hi[mm][nn] += xh.x * ch[nn].x;
                        acc_hi[mm][nn] += xh.y * ch[nn].y;
                        acc_hi[mm][nn] += xh.z * ch[nn].z;
                        acc_hi[mm][nn] += xh.w * ch[nn].w;
                    }
                }
            }
        }

        if (mt == 0) {
            // reduce stats across the 16 tc lanes, preserving tc parity
            // (even tc partials = lo dims, odd tc = hi dims)
#pragma unroll
            for (int m = 2; m < 16; m <<= 1) {
#pragma unroll
                for (int pass = 0; pass < 4; ++pass) {
                    sp[pass] += __shfl_xor(sp[pass], m);
                    qp[pass] += __shfl_xor(qp[pass], m);
                }
            }
            if (tc < 2) {
#pragma unroll
                for (int pass = 0; pass < 4; ++pass) {
                    int kk = pass * 16 + tr;
                    st_s[tc][kk]     = sp[pass];   // 0=csum_lo, 1=csum_hi
                    st_s[2 + tc][kk] = qp[pass];   // 2=csq_lo,  3=csq_hi
                }
            }
        }
        __syncthreads();   // stats visible before scoring; staging of mt=1
                           // can't start until all waves pass the next barrier

        // ---- scoring + argmin ----
        float stl[4], sth[4], stql[4], stqh[4];
#pragma unroll
        for (int nn = 0; nn < 4; ++nn) {
            int kk = nn * 16 + tc;
            stl[nn]  = st_s[0][kk];
            sth[nn]  = st_s[1][kk];
            stql[nn] = st_s[2][kk];
            stqh[nn] = st_s[3][kk];
        }
        // row = mt*128 + mm*16 + tr  ->  a = mt*8 + mm, i = tr
#pragma unroll
        for (int mm = 0; mm < 8; ++mm) {
            const int a = mt * 8 + mm;
            const int ii = tr;
            const int row = mt * 128 + mm * 16 + tr;
            const float xl = xsum[row], xh = xsum[256 + row];
            unsigned long long kA = ~0ULL, kB = ~0ULL;
#pragma unroll
            for (int nn = 0; nn < 4; ++nn) {
                unsigned k = (unsigned)(k0 + nn * 16 + tc);
                float dl = acc_lo[mm][nn], dh = acc_hi[mm][nn];
                float lo_d = stql[nn] - 2.f * dl;
                float lo_m = (384.f - 2.f * stl[nn] + stql[nn]) - 2.f * (xl - dl);
                float hi_d = stqh[nn] - 2.f * dh;
                float hi_m = (384.f - 2.f * sth[nn] + stqh[nn]) - 2.f * (xh - dh);
                if (ii < 7) {
                    kA = umin64(kA, umin64(fkey(lo_d, k), fkey(lo_m, k + 32768u)));
                    kB = umin64(kB, umin64(fkey(hi_d, k), fkey(hi_m, k + 32768u)));
                } else {
                    float fu_d = lo_d + hi_d, fu_m = lo_m + hi_m;
                    kA = umin64(kA, umin64(fkey(fu_d, k), fkey(fu_m, k + 32768u)));
                }
            }
            // reduce across the 16 lanes sharing this row
#pragma unroll
            for (int m = 1; m < 16; m <<= 1) {
                kA = umin64(kA, __shfl_xor(kA, m));
                kB = umin64(kB, __shfl_xor(kB, m));
            }
            if (tc == 0) {
                if (ii < 7) {
                    atomicMin(&sb[a * 23 + ii], kA);
                    atomicMin(&sb[a * 23 + 7 + ii], kB);
                } else {
                    atomicMin(&sb[a * 23 + 14 + (ii - 7)], kA);
                }
            }
        }
    }
}

// ---------------------------------------------------------------------------
// Kernel 3: emit bits. out[a][0:6]=0; bit b: stream s=b/22, bit bb=b%22.
// ---------------------------------------------------------------------------
extern "C" __global__ __launch_bounds__(512)
void bits_kernel(const unsigned long long* __restrict__ sb, float* __restrict__ out) {
    const int a = blockIdx.x;
    const int pos = threadIdx.x;   // 0..511
    float v = 0.f;
    if (pos >= 6) {
        int b = pos - 6;
        int s = b / 22;
        int bb = b - s * 22;
        unsigned idx = (unsigned)(sb[a * 23 + s] & 0xFFFFFFFFu);
        v = (float)((idx >> bb) & 1u);
    }
    out[a * 512 + pos] = v;
}

extern "C" void kernel_launch(void* const* d_in, const int* in_sizes, int n_in,
                              void* d_out, int out_size, void* d_ws, size_t ws_size,
                              hipStream_t stream) {
    const float* x  = (const float*)d_in[0];   // [16,2,126,128]
    const float* cb = (const float*)d_in[1];   // [32768,2,48,8]
    float* ws    = (float*)d_ws;
    float* XS    = ws;                         // 256*768 floats
    float* xsum  = ws + 196608;                // 512 floats (lo then hi)
    unsigned long long* sb = (unsigned long long*)(ws + 197120); // 368 u64
    float* out = (float*)d_out;

    prep_kernel<<<256, 256, 0, stream>>>(x, XS, xsum, sb);
    gemm_kernel<<<K_CB / 64, 256, 0, stream>>>(cb, XS, xsum, sb);
    bits_kernel<<<16, 512, 0, stream>>>(sb, out);
}

// Round 3
// 108.556 us; speedup vs baseline: 5.9100x; 3.6230x over previous
//
#include <hip/hip_runtime.h>
#include <stdint.h>

#define K_CB 32768
typedef unsigned long long u64;
typedef __attribute__((ext_vector_type(8))) short bf16x8;
typedef __attribute__((ext_vector_type(4))) float f32x4;

__device__ __forceinline__ u64 fkey(float f, unsigned idx) {
    unsigned u = __float_as_uint(f);
    u = (u & 0x80000000u) ? ~u : (u | 0x80000000u);
    return ((u64)u << 32) | (u64)idx;
}
__device__ __forceinline__ u64 umin64(u64 a, u64 b) { return a < b ? a : b; }
__device__ __forceinline__ unsigned short f2bf(float f) {   // RNE fp32->bf16
    unsigned u = __float_as_uint(f);
    return (unsigned short)((u + 0x7FFFu + ((u >> 16) & 1u)) >> 16);
}
__device__ __forceinline__ float bf2f(unsigned short b) {
    return __uint_as_float((unsigned)b << 16);
}

// ---------------------------------------------------------------------------
// Kernel 1: split x into two bf16 planes X1,X2 (x = X1 + X2 + eps), stored
// [row=256][col=768] with cols 0..383 = lo dims (j<4), 384..767 = hi (j>=4),
// col-within-parity = (p*48+q)*4 + (j&3)  -- matches the GEMM's K layout.
// Also: xsum_lo/hi per row (fp32, original values) and scoreboard init.
// ---------------------------------------------------------------------------
extern "C" __global__ __launch_bounds__(256)
void prep_kernel(const float* __restrict__ x, unsigned short* __restrict__ X1,
                 unsigned short* __restrict__ X2, float* __restrict__ xsum,
                 u64* __restrict__ sb) {
    __shared__ float xbuf[768];
    const int row = blockIdx.x;          // 0..255
    const int a = row >> 4, i = row & 15;
    for (int pass = 0; pass < 3; ++pass) {
        int t = pass * 256 + threadIdx.x;          // 0..767
        int g = t >> 3, j = t & 7;
        int p = g / 48, q = g - 48 * p;
        float v = x[((size_t)(a * 2 + p) * 126 + (19 + q)) * 128 + (i * 8 + j)];
        xbuf[t] = v;
        unsigned short b1 = f2bf(v);
        float r1 = v - bf2f(b1);
        unsigned short b2 = f2bf(r1);
        int dcol = ((j < 4) ? 0 : 384) + g * 4 + (j & 3);
        X1[(size_t)row * 768 + dcol] = b1;
        X2[(size_t)row * 768 + dcol] = b2;
    }
    __syncthreads();
    if (threadIdx.x < 2) {
        int off = threadIdx.x ? 4 : 0;
        float s = 0.f;
        for (int g = 0; g < 96; ++g)
            for (int j = 0; j < 4; ++j)
                s += xbuf[g * 8 + off + j];
        xsum[threadIdx.x * 256 + row] = s;
    }
    if (row == 0) {
        for (int t = threadIdx.x; t < 368; t += 256) sb[t] = ~0ULL;
    }
}

// ---------------------------------------------------------------------------
// Kernel 2: MFMA GEMM + fused codebook split/stats + scoring + argmin.
// Block = 128 entries x 256 rows, 8 waves (2 e-halves x 4 r-quarters),
// wave tile 64e x 64r = 4x4 fragments of mfma_f32_16x16x32_bf16.
// K = 768 raw in 12 chunks of 64 (-> 32 lo + 32 hi per chunk).
// cross = (x1+x2)(c1+c2): 4 MFMA products, fp32-accurate to ~1e-5.
// Codebook is read once (fp32), split to bf16 c1/c2 during LDS staging;
// per-entry stats (csum/csq lo/hi) accumulate off the same loads.
// LDS tiles stride-40 shorts: 16B-aligned b128, 2-way banks (free).
// ---------------------------------------------------------------------------
extern "C" __global__ __launch_bounds__(512, 2)
void gemm_kernel(const float* __restrict__ cb, const unsigned short* __restrict__ X1,
                 const unsigned short* __restrict__ X2, const float* __restrict__ xsum,
                 u64* __restrict__ sb) {
    __shared__ __align__(16) unsigned short c1t[2][128][40];
    __shared__ __align__(16) unsigned short c2t[2][128][40];
    __shared__ __align__(16) unsigned short x1t[2][256][40];
    __shared__ __align__(16) unsigned short x2t[2][256][40];
    __shared__ float stats_s[4][128];   // 0=csum_lo 1=csum_hi 2=csq_lo 3=csq_hi

    const int tid = threadIdx.x;
    const int lane = tid & 63;
    const int wid = tid >> 6;
    const int k0 = blockIdx.x * 128;
    const int eb = (wid & 1) * 64;      // wave entry base
    const int rb = (wid >> 1) * 64;     // wave row base

    const int eS = tid >> 4;            // 0..31; entry = eS + 32*q
    const int o  = tid & 15;            // f4 slot within entry row
    const int op = o & 1;               // parity of my cb f4s (0=lo,1=hi)
    const int og = o >> 1;              // chunk-local group 0..7

    f32x4 acc[2][4][4] = {};            // [parity][m][n]
    float sp[4] = {0.f,0.f,0.f,0.f}, qp[4] = {0.f,0.f,0.f,0.f};

    for (int c = 0; c < 12; ++c) {
        __syncthreads();
        // ---- stage codebook: 128e x 64 raw fp32 -> c1/c2 bf16, deinterleaved
        float4 cv[4];
#pragma unroll
        for (int q = 0; q < 4; ++q) {
            int e = eS + 32 * q;
            cv[q] = *(const float4*)(cb + (size_t)(k0 + e) * 768 + c * 64 + o * 4);
        }
#pragma unroll
        for (int q = 0; q < 4; ++q) {
            int e = eS + 32 * q;
            float4 v = cv[q];
            sp[q] += v.x + v.y + v.z + v.w;
            qp[q] += v.x * v.x + v.y * v.y + v.z * v.z + v.w * v.w;
            unsigned short ax = f2bf(v.x), ay = f2bf(v.y), az = f2bf(v.z), aw = f2bf(v.w);
            unsigned short bx = f2bf(v.x - bf2f(ax)), by = f2bf(v.y - bf2f(ay));
            unsigned short bz = f2bf(v.z - bf2f(az)), bw = f2bf(v.w - bf2f(aw));
            *(ushort4*)&c1t[op][e][og * 4] = make_ushort4(ax, ay, az, aw);
            *(ushort4*)&c2t[op][e][og * 4] = make_ushort4(bx, by, bz, bw);
        }
        // ---- stage xs: 4 tiles x 256r x 32k bf16 (pure copy from L2)
#pragma unroll
        for (int s = 0; s < 2; ++s) {
            int u = tid + 512 * s;
            int r = u >> 2, qq = u & 3;
            size_t b0 = (size_t)r * 768 + c * 32 + qq * 8;
            *(float4*)&x1t[0][r][qq * 8] = *(const float4*)(X1 + b0);
            *(float4*)&x1t[1][r][qq * 8] = *(const float4*)(X1 + b0 + 384);
            *(float4*)&x2t[0][r][qq * 8] = *(const float4*)(X2 + b0);
            *(float4*)&x2t[1][r][qq * 8] = *(const float4*)(X2 + b0 + 384);
        }
        if (c == 11) {
            // fold per-slot stats across the 16 lanes of each entry group,
            // preserving slot parity (masks 2,4,8): lane o=0 -> lo, o=1 -> hi
#pragma unroll
            for (int m_ = 2; m_ <= 8; m_ <<= 1)
#pragma unroll
                for (int q = 0; q < 4; ++q) {
                    sp[q] += __shfl_xor(sp[q], m_);
                    qp[q] += __shfl_xor(qp[q], m_);
                }
            if (o < 2) {
#pragma unroll
                for (int q = 0; q < 4; ++q) {
                    int e = eS + 32 * q;
                    stats_s[o][e]     = sp[q];
                    stats_s[2 + o][e] = qp[q];
                }
            }
        }
        __syncthreads();
        // ---- MFMA: 2 parities x 4x4 frags x 4 products
        const int koff = (lane >> 4) * 8;
#pragma unroll
        for (int par = 0; par < 2; ++par) {
            bf16x8 A1[4], A2[4], B1[4], B2[4];
#pragma unroll
            for (int m = 0; m < 4; ++m) {
                int er = eb + m * 16 + (lane & 15);
                A1[m] = *(const bf16x8*)&c1t[par][er][koff];
                A2[m] = *(const bf16x8*)&c2t[par][er][koff];
            }
#pragma unroll
            for (int n = 0; n < 4; ++n) {
                int rr = rb + n * 16 + (lane & 15);
                B1[n] = *(const bf16x8*)&x1t[par][rr][koff];
                B2[n] = *(const bf16x8*)&x2t[par][rr][koff];
            }
#pragma unroll
            for (int m = 0; m < 4; ++m)
#pragma unroll
                for (int n = 0; n < 4; ++n) {
                    acc[par][m][n] = __builtin_amdgcn_mfma_f32_16x16x32_bf16(A1[m], B1[n], acc[par][m][n], 0, 0, 0);
                    acc[par][m][n] = __builtin_amdgcn_mfma_f32_16x16x32_bf16(A2[m], B1[n], acc[par][m][n], 0, 0, 0);
                    acc[par][m][n] = __builtin_amdgcn_mfma_f32_16x16x32_bf16(A1[m], B2[n], acc[par][m][n], 0, 0, 0);
                    acc[par][m][n] = __builtin_amdgcn_mfma_f32_16x16x32_bf16(A2[m], B2[n], acc[par][m][n], 0, 0, 0);
                }
        }
    }

    // ---- scoring + argmin epilogue ----
    // D layout: col (N=row r) = lane&15, row (M=entry) = (lane>>4)*4 + reg
    const int i_ = lane & 15;
#pragma unroll
    for (int n = 0; n < 4; ++n) {
        const int r = rb + n * 16 + i_;
        const float xl = xsum[r], xh = xsum[256 + r];
        u64 kA = ~0ULL, kB = ~0ULL;
#pragma unroll
        for (int m = 0; m < 4; ++m) {
#pragma unroll
            for (int reg = 0; reg < 4; ++reg) {
                int el = eb + m * 16 + ((lane >> 4) << 2) + reg;
                unsigned kg = (unsigned)(k0 + el);
                float stl = stats_s[0][el], sth = stats_s[1][el];
                float stql = stats_s[2][el], stqh = stats_s[3][el];
                float dl = acc[0][m][n][reg], dh = acc[1][m][n][reg];
                float lo_d = stql - 2.f * dl;
                float lo_m = (384.f - 2.f * stl + stql) - 2.f * (xl - dl);
                float hi_d = stqh - 2.f * dh;
                float hi_m = (384.f - 2.f * sth + stqh) - 2.f * (xh - dh);
                if (i_ < 7) {
                    kA = umin64(kA, umin64(fkey(lo_d, kg), fkey(lo_m, kg + 32768u)));
                    kB = umin64(kB, umin64(fkey(hi_d, kg), fkey(hi_m, kg + 32768u)));
                } else {
                    kA = umin64(kA, umin64(fkey(lo_d + hi_d, kg), fkey(lo_m + hi_m, kg + 32768u)));
                }
            }
        }
        kA = umin64(kA, __shfl_xor(kA, 16));
        kA = umin64(kA, __shfl_xor(kA, 32));
        kB = umin64(kB, __shfl_xor(kB, 16));
        kB = umin64(kB, __shfl_xor(kB, 32));
        if (lane < 16) {
            int a_ = r >> 4;
            if (i_ < 7) {
                atomicMin(&sb[a_ * 23 + i_], kA);
                atomicMin(&sb[a_ * 23 + 7 + i_], kB);
            } else {
                atomicMin(&sb[a_ * 23 + 14 + (i_ - 7)], kA);
            }
        }
    }
}

// ---------------------------------------------------------------------------
// Kernel 3: emit bits. out[a][0:6]=0; bit b: stream s=b/22, bit bb=b%22.
// ---------------------------------------------------------------------------
extern "C" __global__ __launch_bounds__(512)
void bits_kernel(const u64* __restrict__ sb, float* __restrict__ out) {
    const int a = blockIdx.x;
    const int pos = threadIdx.x;   // 0..511
    float v = 0.f;
    if (pos >= 6) {
        int b = pos - 6;
        int s = b / 22;
        int bb = b - s * 22;
        unsigned idx = (unsigned)(sb[a * 23 + s] & 0xFFFFFFFFu);
        v = (float)((idx >> bb) & 1u);
    }
    out[a * 512 + pos] = v;
}

extern "C" void kernel_launch(void* const* d_in, const int* in_sizes, int n_in,
                              void* d_out, int out_size, void* d_ws, size_t ws_size,
                              hipStream_t stream) {
    const float* x  = (const float*)d_in[0];   // [16,2,126,128]
    const float* cb = (const float*)d_in[1];   // [32768,2,48,8]
    char* ws = (char*)d_ws;
    unsigned short* X1 = (unsigned short*)ws;                 // 256*768 bf16
    unsigned short* X2 = (unsigned short*)(ws + 393216);      // 256*768 bf16
    float* xsum        = (float*)(ws + 786432);               // 512 f32
    u64*   sb          = (u64*)(ws + 788480);                 // 368 u64
    float* out = (float*)d_out;

    prep_kernel<<<256, 256, 0, stream>>>(x, X1, X2, xsum, sb);
    gemm_kernel<<<256, 512, 0, stream>>>(cb, X1, X2, xsum, sb);
    bits_kernel<<<16, 512, 0, stream>>>(sb, out);
}

// Round 5
// 69.821 us; speedup vs baseline: 9.1887x; 1.5548x over previous
//
#include <hip/hip_runtime.h>
#include <stdint.h>

typedef unsigned long long u64;
typedef unsigned int u32;
typedef __attribute__((ext_vector_type(8))) short bf16x8;
typedef __attribute__((ext_vector_type(4))) float f32x4;

__device__ __forceinline__ u64 fkey(float f, unsigned idx) {
    unsigned u = __float_as_uint(f);
    u = (u & 0x80000000u) ? ~u : (u | 0x80000000u);
    return ((u64)u << 32) | (u64)idx;
}
__device__ __forceinline__ u64 umin64(u64 a, u64 b) { return a < b ? a : b; }
__device__ __forceinline__ unsigned short f2bf(float f) {   // RNE fp32->bf16
    unsigned u = __float_as_uint(f);
    return (unsigned short)((u + 0x7FFFu + ((u >> 16) & 1u)) >> 16);
}
__device__ __forceinline__ float bf2f(unsigned short b) {
    return __uint_as_float((unsigned)b << 16);
}

// ---------------------------------------------------------------------------
// Kernel 1: split x into bf16 planes, stored LINEAR: Xs[row][plane][chunk][col64]
// (row stride 1536 shorts, plane stride 768). col64 = par*32 + (colin&31),
// colin = (p*48+q)*4 + (j&3), chunk = colin>>5. The granule swizzle is applied
// ONCE, by gemm's per-lane global_load_lds source offset (rule 21: exactly one
// source-side permutation + matching swizzled read).
// Also: xsum_lo/hi per row, and global scoreboard init.
// ---------------------------------------------------------------------------
extern "C" __global__ __launch_bounds__(256)
void prep_kernel(const float* __restrict__ x, unsigned short* __restrict__ Xs,
                 float* __restrict__ xsum, u64* __restrict__ sb) {
    __shared__ float xbuf[768];
    const int row = blockIdx.x;          // 0..255
    const int a = row >> 4, i = row & 15;
    for (int pass = 0; pass < 3; ++pass) {
        int t = pass * 256 + threadIdx.x;          // 0..767
        int g = t >> 3, j = t & 7;
        int p = g / 48, q = g - 48 * p;
        float v = x[((size_t)(a * 2 + p) * 126 + (19 + q)) * 128 + (i * 8 + j)];
        xbuf[t] = v;
        unsigned short b1 = f2bf(v);
        unsigned short b2 = f2bf(v - bf2f(b1));
        int par = (j >> 2);                        // 0 = lo, 1 = hi
        int colin = g * 4 + (j & 3);               // 0..383 within parity
        int c = colin >> 5;                        // chunk 0..11
        int col64 = par * 32 + (colin & 31);       // 0..63 within chunk-row
        size_t base = (size_t)row * 1536 + c * 64 + col64;
        Xs[base] = b1;            // plane 0 (x1)
        Xs[base + 768] = b2;      // plane 1 (x2)
    }
    __syncthreads();
    if (threadIdx.x < 2) {
        int off = threadIdx.x ? 4 : 0;
        float s = 0.f;
        for (int g = 0; g < 96; ++g)
            for (int j = 0; j < 4; ++j)
                s += xbuf[g * 8 + off + j];
        xsum[threadIdx.x * 256 + row] = s;
    }
    if (row == 0) {
        for (int t = threadIdx.x; t < 368; t += 256) sb[t] = ~0ULL;
    }
}

// ---------------------------------------------------------------------------
// Kernel 2: MFMA GEMM, 64 entries x 256 rows per block, grid 512, 2 blocks/CU
// (LDS exactly 80KB). K = 12 chunks of 64 raw dims (cols 0-31 lo, 32-63 hi).
// LDS rows are 128B of 8 16B-granules; logical granule g of row r sits at
// position g ^ (r&7) -> conflict-free ds_read_b128 (T2 geometry).
//   cb: fp32 read once, split to c1/c2 + stats fused in staging (reg path,
//       swizzled ds_write).
//   X:  global_load_lds, swizzle produced by per-lane source offset
//       gswz = (lane&7) ^ (lane>>3), LDS dest linear (m104/m173 discipline).
// Epilogue: exact u64-key argmin -> LDS scoreboard -> 368 global atomicMin.
// ---------------------------------------------------------------------------
extern "C" __global__ __launch_bounds__(512, 4)
void gemm_kernel(const float* __restrict__ cb, const unsigned short* __restrict__ Xs,
                 const float* __restrict__ xsum, u64* __restrict__ sb) {
    __shared__ __align__(16) unsigned short cbt[128][64];   // 16KB
    __shared__ __align__(16) unsigned short xst[512][64];   // 64KB

    const int tid = threadIdx.x;
    const int lane = tid & 63;
    const int wid = tid >> 6;
    const int k0 = blockIdx.x * 64;
    const int eb = (wid & 1) * 32;      // wave entry base (within 64)
    const int rb = (wid >> 1) * 64;     // wave row base
    const int l15 = lane & 15;
    const int g4 = lane >> 4;
    const int h7 = lane & 7;

    // cb staging geometry: e=tid>>4 (0..31), group sgl=(tid>>1)&7, half=tid&1
    const int se = tid >> 4;
    const int sgl = (tid >> 1) & 7;
    const int shalf = tid & 1;
    const int scol = shalf * 32 + sgl * 4;
    const int ssw = (((scol >> 3) ^ (se & 7)) << 3) + (sgl & 1) * 4; // shorts

    // xs source swizzle: lane covers LDS row (base + lane>>3), granule lane&7;
    // source granule = (lane&7) ^ (row&7), row&7 == lane>>3 (base % 8 == 0)
    const int gswz = h7 ^ (lane >> 3);

    f32x4 acc[2][2][4] = {};            // [parity][m][n]
    float sp0 = 0.f, sq0 = 0.f, sp1 = 0.f, sq1 = 0.f;

    for (int c = 0; c < 12; ++c) {
        __syncthreads();
        // ---- stage cb: 64e x 8 groups x 16B fp32 -> split -> swizzled LDS
        const float* s1 = cb + (size_t)(k0 + se) * 768 + (c * 8 + sgl) * 8 + shalf * 4;
        float4 v1 = *(const float4*)s1;
        float4 v2 = *(const float4*)(s1 + 32 * 768);
        sp0 += v1.x + v1.y + v1.z + v1.w;
        sq0 += v1.x * v1.x + v1.y * v1.y + v1.z * v1.z + v1.w * v1.w;
        sp1 += v2.x + v2.y + v2.z + v2.w;
        sq1 += v2.x * v2.x + v2.y * v2.y + v2.z * v2.z + v2.w * v2.w;
        unsigned short a1x = f2bf(v1.x), a1y = f2bf(v1.y), a1z = f2bf(v1.z), a1w = f2bf(v1.w);
        unsigned short a2x = f2bf(v2.x), a2y = f2bf(v2.y), a2z = f2bf(v2.z), a2w = f2bf(v2.w);
        ushort4 c1a = make_ushort4(a1x, a1y, a1z, a1w);
        ushort4 c1b = make_ushort4(f2bf(v1.x - bf2f(a1x)), f2bf(v1.y - bf2f(a1y)),
                                   f2bf(v1.z - bf2f(a1z)), f2bf(v1.w - bf2f(a1w)));
        ushort4 c2a = make_ushort4(a2x, a2y, a2z, a2w);
        ushort4 c2b = make_ushort4(f2bf(v2.x - bf2f(a2x)), f2bf(v2.y - bf2f(a2y)),
                                   f2bf(v2.z - bf2f(a2z)), f2bf(v2.w - bf2f(a2w)));
        *(ushort4*)&cbt[se][ssw]      = c1a;   // rows se,se+32,se+64,se+96 share se&7
        *(ushort4*)&cbt[se + 64][ssw] = c1b;
        *(ushort4*)&cbt[se + 32][ssw] = c2a;
        *(ushort4*)&cbt[se + 96][ssw] = c2b;
        // ---- stage xs: 64KB via global_load_lds (per-lane swizzled source)
#pragma unroll
        for (int i = 0; i < 8; ++i) {
            int row = (wid << 6) + (i << 3) + (lane >> 3);
            const unsigned short* gs = Xs + (size_t)(row & 255) * 1536 + (row >> 8) * 768
                                          + c * 64 + gswz * 8;
            __builtin_amdgcn_global_load_lds(
                (const __attribute__((address_space(1))) u32*)gs,
                (__attribute__((address_space(3))) u32*)&xst[(wid << 6) + (i << 3)][0],
                16, 0, 0);
        }
        __syncthreads();
        // ---- MFMA: per parity: 2m x 4n frags x 4 split products (K=32 each)
#pragma unroll
        for (int par = 0; par < 2; ++par) {
            const int sws = ((((par << 2) | g4) ^ h7) << 3);
            bf16x8 A1[2], A2[2];
#pragma unroll
            for (int m = 0; m < 2; ++m) {
                A1[m] = *(const bf16x8*)&cbt[eb + m * 16 + l15][sws];
                A2[m] = *(const bf16x8*)&cbt[eb + m * 16 + l15 + 64][sws];
            }
#pragma unroll
            for (int n = 0; n < 4; ++n) {
                const unsigned short* xr = &xst[rb + n * 16 + l15][sws];
                bf16x8 B1 = *(const bf16x8*)xr;
                bf16x8 B2 = *(const bf16x8*)(xr + 256 * 64);
#pragma unroll
                for (int m = 0; m < 2; ++m) {
                    acc[par][m][n] = __builtin_amdgcn_mfma_f32_16x16x32_bf16(A1[m], B1, acc[par][m][n], 0, 0, 0);
                    acc[par][m][n] = __builtin_amdgcn_mfma_f32_16x16x32_bf16(A2[m], B1, acc[par][m][n], 0, 0, 0);
                    acc[par][m][n] = __builtin_amdgcn_mfma_f32_16x16x32_bf16(A1[m], B2, acc[par][m][n], 0, 0, 0);
                    acc[par][m][n] = __builtin_amdgcn_mfma_f32_16x16x32_bf16(A2[m], B2, acc[par][m][n], 0, 0, 0);
                }
            }
        }
    }

    // ---- finalize stats: reduce over group lanes (masks 2,4,8 keep parity bit0)
#pragma unroll
    for (int m = 2; m <= 8; m <<= 1) {
        sp0 += __shfl_xor(sp0, m); sq0 += __shfl_xor(sq0, m);
        sp1 += __shfl_xor(sp1, m); sq1 += __shfl_xor(sq1, m);
    }
    __syncthreads();                    // all MFMA-phase ds_reads done; cbt dead
    float* stf = (float*)&cbt[0][0];    // [0..63]=csum_lo [64..]=csq_lo [128..]=csum_hi [192..]=csq_hi
    u64* msb = (u64*)((char*)&cbt[0][0] + 1024);   // 368-entry LDS scoreboard
    if ((tid & 15) < 2) {
        int par = tid & 1, e = tid >> 4;
        stf[par * 128 + e]           = sp0;
        stf[par * 128 + 64 + e]      = sq0;
        stf[par * 128 + e + 32]      = sp1;
        stf[par * 128 + 64 + e + 32] = sq1;
    }
    if (tid < 368) msb[tid] = ~0ULL;
    __syncthreads();

    // ---- scoring + argmin: D layout col(N=row)=lane&15, row(M)=(lane>>4)*4+reg
#pragma unroll
    for (int n = 0; n < 4; ++n) {
        const int r = rb + n * 16 + l15;
        const float xl = xsum[r], xh = xsum[256 + r];
        u64 kA = ~0ULL, kB = ~0ULL;
#pragma unroll
        for (int m = 0; m < 2; ++m) {
#pragma unroll
            for (int reg = 0; reg < 4; ++reg) {
                const int el = eb + m * 16 + (g4 << 2) + reg;
                const unsigned kg = (unsigned)(k0 + el);
                float stl = stf[el],       sql = stf[64 + el];
                float sth = stf[128 + el], sqh = stf[192 + el];
                float dl = acc[0][m][n][reg], dh = acc[1][m][n][reg];
                float lo_d = sql - 2.f * dl;
                float lo_m = (384.f - 2.f * stl + sql) - 2.f * (xl - dl);
                float hi_d = sqh - 2.f * dh;
                float hi_m = (384.f - 2.f * sth + sqh) - 2.f * (xh - dh);
                if (l15 < 7) {
                    kA = umin64(kA, umin64(fkey(lo_d, kg), fkey(lo_m, kg + 32768u)));
                    kB = umin64(kB, umin64(fkey(hi_d, kg), fkey(hi_m, kg + 32768u)));
                } else {
                    kA = umin64(kA, umin64(fkey(lo_d + hi_d, kg), fkey(lo_m + hi_m, kg + 32768u)));
                }
            }
        }
        kA = umin64(kA, __shfl_xor(kA, 16));
        kA = umin64(kA, __shfl_xor(kA, 32));
        kB = umin64(kB, __shfl_xor(kB, 16));
        kB = umin64(kB, __shfl_xor(kB, 32));
        if (lane < 16) {
            int a_ = r >> 4;
            if (l15 < 7) {
                atomicMin(&msb[a_ * 23 + l15], kA);
                atomicMin(&msb[a_ * 23 + 7 + l15], kB);
            } else {
                atomicMin(&msb[a_ * 23 + 14 + (l15 - 7)], kA);
            }
        }
    }
    __syncthreads();
    if (tid < 368) atomicMin(&sb[tid], msb[tid]);
}

// ---------------------------------------------------------------------------
// Kernel 3: emit bits. out[a][0:6]=0; bit b: stream s=b/22, bit bb=b%22.
// ---------------------------------------------------------------------------
extern "C" __global__ __launch_bounds__(512)
void bits_kernel(const u64* __restrict__ sb, float* __restrict__ out) {
    const int a = blockIdx.x;
    const int pos = threadIdx.x;   // 0..511
    float v = 0.f;
    if (pos >= 6) {
        int b = pos - 6;
        int s = b / 22;
        int bb = b - s * 22;
        unsigned idx = (unsigned)(sb[a * 23 + s] & 0xFFFFFFFFu);
        v = (float)((idx >> bb) & 1u);
    }
    out[a * 512 + pos] = v;
}

extern "C" void kernel_launch(void* const* d_in, const int* in_sizes, int n_in,
                              void* d_out, int out_size, void* d_ws, size_t ws_size,
                              hipStream_t stream) {
    const float* x  = (const float*)d_in[0];   // [16,2,126,128]
    const float* cb = (const float*)d_in[1];   // [32768,2,48,8]
    char* ws = (char*)d_ws;
    unsigned short* Xs = (unsigned short*)ws;              // 256*1536 bf16 = 768KB
    float* xsum        = (float*)(ws + 786432);            // 512 f32
    u64*   sb          = (u64*)(ws + 788480);              // 368 u64
    float* out = (float*)d_out;

    prep_kernel<<<256, 256, 0, stream>>>(x, Xs, xsum, sb);
    gemm_kernel<<<512, 512, 0, stream>>>(cb, Xs, xsum, sb);
    bits_kernel<<<16, 512, 0, stream>>>(sb, out);
}